// Round 2
// baseline (1161.419 us; speedup 1.0000x reference)
//
#include <hip/hip_runtime.h>
#include <math.h>

// Problem constants
#define BB 4
#define TT 512
#define FF 257
#define NP 10
#define DM 128
#define C2P 20          // 2*P channels
#define KW 5            // conv taps
#define TP 516          // T padded with 2-row zero halo on each side
#define FP 260          // feat row stride (floats)
#define WROW 288        // featT LDS row stride: word = (o&15)*18 + (o>>4), max 286
#define FSTRIDE (2 * TP * FP)   // per-pair advance in feat (2 channels)

// Workspace (floats): stats @0 (10280) ; wT @10304 (12800) ; feat @23104
// (10,732,800). k1 partials (148,032) OVERLAY feat @23104 (dead before k2
// writes feat). Total = 43.0 MB, identical to the proven round-1 footprint.

// ---------------------------------------------------------------------------
// K0: transpose conv weights once: wT[(p*10 + r)*128 + d], r = cl*5 + tap.
// ---------------------------------------------------------------------------
__global__ void k0_wt(const float* __restrict__ convw, float* __restrict__ wT) {
    const int idx = blockIdx.x * 512 + threadIdx.x;
    if (idx >= NP * 10 * DM) return;
    const int p = idx / 1280;
    const int rr = idx - p * 1280;
    const int r = rr >> 7, d = rr & 127;
    const int cl = r / 5, kt = r - cl * 5;
    wT[idx] = convw[(size_t)d * (C2P * KW) + (2 * p + cl) * KW + kt];
}

// ---------------------------------------------------------------------------
// K1a: partial per-(b,f) sums over 32-t chunks. Old k1 was 260 blocks =
// 1 block/CU latency-bound (~200us of the round-0 total). 576 blocks now.
// Block: (b, ftile of 32, chunk of 32 t). 256 thr = 32 f x 8 t-threads.
// Reads fully coalesced (32 consecutive f x 2 float4).
// partial[((b*257+f)*16 + c)*9 + k]: k = 0..3 sum_re, 4..7 sum_im, 8 sum_sq
// ---------------------------------------------------------------------------
__global__ __launch_bounds__(256) void k1a_part(const float* __restrict__ x,
                                                float* __restrict__ partial) {
    const int bid = blockIdx.x;
    const int b = bid / 144;
    const int rem = bid - b * 144;
    const int ft = rem >> 4;          // 0..8
    const int c = rem & 15;           // t-chunk 0..15
    const int tid = threadIdx.x;
    const int fi = tid & 31;
    const int th = tid >> 5;          // 0..7
    const int f = ft * 32 + fi;

    float s[9];
    #pragma unroll
    for (int k = 0; k < 9; k++) s[k] = 0.f;
    if (f < FF) {
        #pragma unroll
        for (int q = 0; q < 4; q++) {
            const int t = c * 32 + th * 4 + q;
            const float* px = x + (((size_t)b * TT + t) * FF + f) * 8;
            const float4 v0 = *(const float4*)px;
            const float4 v1 = *(const float4*)(px + 4);
            s[0] += v0.x; s[1] += v0.y; s[2] += v0.z; s[3] += v0.w;
            s[4] += v1.x; s[5] += v1.y; s[6] += v1.z; s[7] += v1.w;
            s[8] += v0.x*v0.x + v0.y*v0.y + v0.z*v0.z + v0.w*v0.w
                  + v1.x*v1.x + v1.y*v1.y + v1.z*v1.z + v1.w*v1.w;
        }
    }
    __shared__ float red[256][9];
    #pragma unroll
    for (int k = 0; k < 9; k++) red[tid][k] = s[k];
    __syncthreads();
    for (int st = 4; st >= 1; st >>= 1) {
        if (th < st) {
            #pragma unroll
            for (int k = 0; k < 9; k++) red[tid][k] += red[tid + 32 * st][k];
        }
        __syncthreads();
    }
    if (th == 0 && f < FF) {
        float* pp = partial + ((size_t)(b * FF + f) * 16 + c) * 9;
        #pragma unroll
        for (int k = 0; k < 9; k++) pp[k] = red[tid][k];
    }
}

// ---------------------------------------------------------------------------
// K1b: finalize stats from 16 chunk-partials.
// stats[b][f][10]: 0..3 mean_re, 4..7 mean_im, 8 inv_norm
// ---------------------------------------------------------------------------
__global__ __launch_bounds__(320) void k1b_fin(const float* __restrict__ partial,
                                               float* __restrict__ stats) {
    const int b = blockIdx.x;
    const int f = threadIdx.x;
    if (f >= FF) return;
    const float* pp = partial + (size_t)(b * FF + f) * 16 * 9;
    float s[9];
    #pragma unroll
    for (int k = 0; k < 9; k++) s[k] = 0.f;
    for (int c = 0; c < 16; c++) {
        #pragma unroll
        for (int k = 0; k < 9; k++) s[k] += pp[c * 9 + k];
    }
    const float invT = 1.0f / (float)TT;
    float pw = s[8] * invT;
    float* st = stats + ((size_t)b * FF + f) * 10;
    #pragma unroll
    for (int m = 0; m < 4; m++) {
        const float mr = s[m] * invT;
        const float mi = s[4 + m] * invT;
        st[m] = mr; st[4 + m] = mi;
        pw -= mr * mr + mi * mi;
    }
    st[8] = rsqrtf(fmaxf(pw, 1e-10f));
}

// ---------------------------------------------------------------------------
// K2: compute SCM features ONCE -> feat[b][ch=2p+ri][tpad][f], tpad = t+2.
// Halo rows tpad in {0,1,514,515} zero-filled (conv SAME padding).
// ---------------------------------------------------------------------------
__global__ __launch_bounds__(256) void k2_feat(const float* __restrict__ x,
                                               const float* __restrict__ expnt,
                                               const float* __restrict__ ipdf,
                                               const float* __restrict__ stats,
                                               float* __restrict__ feat) {
    const int b = blockIdx.x / TP;
    const int tpad = blockIdx.x % TP;
    const int t = tpad - 2;
    float* fb = feat + ((size_t)b * C2P * TP + tpad) * FP;   // ch stride = TP*FP
    if (t < 0 || t >= TT) {
        for (int idx = threadIdx.x; idx < C2P * FP; idx += 256) {
            const int ch = idx / FP, f = idx - ch * FP;
            fb[(size_t)ch * TP * FP + f] = 0.f;
        }
        return;
    }
    for (int f = threadIdx.x; f < FF; f += 256) {
        const float* px = x + (((size_t)b * TT + t) * FF + f) * 8;
        const float4 v0 = *(const float4*)px;
        const float4 v1 = *(const float4*)(px + 4);
        const float* st = stats + ((size_t)b * FF + f) * 10;
        const float inv = st[8];
        float xr[4], xi[4];
        xr[0] = (v0.x - st[0]) * inv; xr[1] = (v0.y - st[1]) * inv;
        xr[2] = (v0.z - st[2]) * inv; xr[3] = (v0.w - st[3]) * inv;
        xi[0] = (v1.x - st[4]) * inv; xi[1] = (v1.y - st[5]) * inv;
        xi[2] = (v1.z - st[6]) * inv; xi[3] = (v1.w - st[7]) * inv;
        const float sef = 1.0f / (1.0f + __expf(-expnt[f]));
        const float sif = 1.0f / (1.0f + __expf(-ipdf[f]));
        const int MA[NP] = {0,0,0,0,1,1,1,2,2,3};
        const int MB[NP] = {0,1,2,3,1,2,3,2,3,3};
        #pragma unroll
        for (int p = 0; p < NP; p++) {
            const float cra = xr[MA[p]], cia = xi[MA[p]];
            const float crb = xr[MB[p]], cib = xi[MB[p]];
            const float re = cra * crb + cia * cib;
            const float im = cia * crb - cra * cib;
            const float r = sqrtf(re * re + im * im);
            const float bp = exp2f(sef * __log2f(r));   // r=0 -> 0 (matches ref)
            const float a = r / (bp + 1e-10f);
            const float ang = atan2f(im, re) * sif;
            float sn, cs;
            __sincosf(ang, &sn, &cs);
            fb[(size_t)(2 * p) * TP * FP + f] = a * cs;
            fb[(size_t)(2 * p + 1) * TP * FP + f] = a * sn;
        }
    }
}

// ---------------------------------------------------------------------------
// K3: one block per (b,t). Staged GEMM over 10 pairs + fused LayerNorm.
// 512 thr = 32 d-threads (4 d) x 16 f-threads (17 f, f = ftid+16j).
//
// Round-1 post-mortem fixes:
//  (a) VGPR=128 spill (WRITE_SIZE 2.15GB vs 269MB output): persistent staging
//      state cut to ~20 regs via shift-only addressing (10 rows x 256 = 5
//      exact slots, f=256 column via 10-thread side channel); p-loop pinned
//      with unroll(1).
//  (b) SQ_LDS_BANK_CONFLICT 4.77e7: chunk stride 20 (even) made b128 start
//      banks alias pairwise (20*ftid mod 32: ftid vs ftid+8). New layout:
//      word = (o&15)*18 + (o>>4), read as 8x ds_read_b64. 18*ftid mod 32
//      covers all 16 even residues exactly once -> every word-phase hits all
//      32 banks once. Conflict-free under any phasing model.
// ---------------------------------------------------------------------------
__global__ __launch_bounds__(512, 2) void k3_conv_ln(
        const float* __restrict__ feat,
        const float* __restrict__ wT,
        const float* __restrict__ convb,
        const float* __restrict__ lnw,
        const float* __restrict__ lnb,
        float* __restrict__ out) {
    const int bid = blockIdx.x;
    const int bt = (bid & 7) * 256 + (bid >> 3);  // XCD swizzle (2048 % 8 == 0)
    const int b = bt >> 9;
    const int t = bt & 511;
    const int tid = threadIdx.x;
    const int ftid = tid & 15;
    const int dtid = tid >> 4;      // 0..31
    const int d0 = dtid * 4;

    __shared__ __align__(16) float featT[2][NP * WROW];  // 23040 B
    __shared__ __align__(16) float wcs[2][NP * DM];      // 10240 B
    __shared__ float wred[16];

    // staging addresses: i = tid + 512u (u<5) covers 10 rows x 256 f exactly.
    int gsrc[5], gdst[5];
    #pragma unroll
    for (int u = 0; u < 5; u++) {
        const int i = tid + 512 * u;
        const int r = i >> 8, o = i & 255;       // row 0..9, f 0..255
        const int cl = (r >= 5) ? 1 : 0;
        const int kt = r - 5 * cl;
        gsrc[u] = ((b * C2P + cl) * TP + (t + kt)) * FP + o;   // + p*FSTRIDE
        gdst[u] = r * WROW + (o & 15) * 18 + (o >> 4);
    }
    int gsx = 0;
    {   // f = 256 column: threads 0..9 handle row r = tid
        const int r = tid;
        const int cl = (r >= 5) ? 1 : 0;
        const int kt = r - 5 * cl;
        gsx = ((b * C2P + cl) * TP + (t + kt)) * FP + 256;     // valid for tid<10
    }

    float sv[5], svx = 0.f, wv[3];
    // prologue: stage pair 0
    #pragma unroll
    for (int u = 0; u < 5; u++) sv[u] = feat[gsrc[u]];
    if (tid < 10) svx = feat[gsx];
    #pragma unroll
    for (int u = 0; u < 3; u++) { const int i = tid + 512 * u; if (i < 1280) wv[u] = wT[i]; }
    #pragma unroll
    for (int u = 0; u < 5; u++) featT[0][gdst[u]] = sv[u];
    if (tid < 10) featT[0][tid * WROW + 16] = svx;
    #pragma unroll
    for (int u = 0; u < 3; u++) { const int i = tid + 512 * u; if (i < 1280) wcs[0][i] = wv[u]; }
    __syncthreads();

    float acc[4][17];
    #pragma unroll
    for (int i = 0; i < 4; i++)
        #pragma unroll
        for (int j = 0; j < 17; j++) acc[i][j] = 0.f;

    int cur = 0;
    #pragma unroll 1
    for (int p = 0; p < NP; p++) {
        // prefetch pair p+1 into registers (hidden under this pair's FMAs)
        if (p < NP - 1) {
            #pragma unroll
            for (int u = 0; u < 5; u++) sv[u] = feat[gsrc[u] + (p + 1) * FSTRIDE];
            if (tid < 10) svx = feat[gsx + (p + 1) * FSTRIDE];
            #pragma unroll
            for (int u = 0; u < 3; u++) {
                const int i = tid + 512 * u;
                if (i < 1280) wv[u] = wT[(p + 1) * 1280 + i];
            }
        }

        const float* fT = featT[cur];
        const float* wc = wcs[cur];
        #pragma unroll
        for (int kk = 0; kk < NP; kk++) {
            const float4 w = *(const float4*)(wc + kk * DM + d0);
            const float* bp_ = fT + kk * WROW + ftid * 18;
            const float2 q0 = *(const float2*)(bp_ + 0);
            const float2 q1 = *(const float2*)(bp_ + 2);
            const float2 q2 = *(const float2*)(bp_ + 4);
            const float2 q3 = *(const float2*)(bp_ + 6);
            const float2 q4 = *(const float2*)(bp_ + 8);
            const float2 q5 = *(const float2*)(bp_ + 10);
            const float2 q6 = *(const float2*)(bp_ + 12);
            const float2 q7 = *(const float2*)(bp_ + 14);
            const float fx = bp_[16];   // j=16 (garbage for ftid>0: masked slot)
            const float fv[17] = {q0.x,q0.y,q1.x,q1.y,q2.x,q2.y,q3.x,q3.y,
                                  q4.x,q4.y,q5.x,q5.y,q6.x,q6.y,q7.x,q7.y,fx};
            const float wa[4] = {w.x, w.y, w.z, w.w};
            #pragma unroll
            for (int i = 0; i < 4; i++)
                #pragma unroll
                for (int j = 0; j < 17; j++)
                    acc[i][j] = fmaf(wa[i], fv[j], acc[i][j]);
        }

        // write next pair into the free buffer; ONE barrier per pair
        if (p < NP - 1) {
            const int nxt = cur ^ 1;
            #pragma unroll
            for (int u = 0; u < 5; u++) featT[nxt][gdst[u]] = sv[u];
            if (tid < 10) featT[nxt][tid * WROW + 16] = svx;
            #pragma unroll
            for (int u = 0; u < 3; u++) {
                const int i = tid + 512 * u;
                if (i < 1280) wcs[nxt][i] = wv[u];
            }
        }
        __syncthreads();
        cur ^= 1;
    }

    // ---- Epilogue: bias + LayerNorm over (d, f<257), coalesced stores ----
    float cb[4];
    #pragma unroll
    for (int i = 0; i < 4; i++) cb[i] = convb[d0 + i];

    float s1 = 0.f, s2 = 0.f;
    const int jmax = (ftid == 0) ? 17 : 16;   // f = ftid + 16*j < 257
    #pragma unroll
    for (int i = 0; i < 4; i++) {
        #pragma unroll
        for (int j = 0; j < 17; j++) {
            acc[i][j] += cb[i];
            if (j < jmax) { s1 += acc[i][j]; s2 += acc[i][j] * acc[i][j]; }
        }
    }
    #pragma unroll
    for (int off = 32; off >= 1; off >>= 1) {
        s1 += __shfl_down(s1, off, 64);
        s2 += __shfl_down(s2, off, 64);
    }
    const int wv8 = tid >> 6;                 // 8 waves
    if ((tid & 63) == 0) { wred[wv8] = s1; wred[8 + wv8] = s2; }
    __syncthreads();
    float S1 = 0.f, S2 = 0.f;
    #pragma unroll
    for (int w = 0; w < 8; w++) { S1 += wred[w]; S2 += wred[8 + w]; }
    const float Ninv = 1.0f / (float)(DM * FF);
    const float mu = S1 * Ninv;
    const float var = S2 * Ninv - mu * mu;
    const float rstd = rsqrtf(var + 1e-5f);

    float* op = out + (size_t)bt * DM * FF;
    #pragma unroll
    for (int i = 0; i < 4; i++) {
        const int d = d0 + i;
        #pragma unroll
        for (int j = 0; j < 17; j++) {
            const int f = ftid + 16 * j;
            if (f < FF) {
                const size_t o = (size_t)d * FF + f;
                op[o] = (acc[i][j] - mu) * rstd * lnw[o] + lnb[o];
            }
        }
    }
}

extern "C" void kernel_launch(void* const* d_in, const int* in_sizes, int n_in,
                              void* d_out, int out_size, void* d_ws, size_t ws_size,
                              hipStream_t stream) {
    const float* x     = (const float*)d_in[0];
    const float* expnt = (const float*)d_in[1];
    const float* ipdf  = (const float*)d_in[2];
    const float* convw = (const float*)d_in[3];
    const float* convb = (const float*)d_in[4];
    const float* lnw   = (const float*)d_in[5];
    const float* lnb   = (const float*)d_in[6];
    float* out = (float*)d_out;

    float* stats   = (float*)d_ws;
    float* wT      = stats + 10304;
    float* feat    = stats + 23104;
    float* partial = feat;          // overlay: dead before k2 writes feat

    k0_wt<<<25, 512, 0, stream>>>(convw, wT);
    k1a_part<<<BB * 144, 256, 0, stream>>>(x, partial);
    k1b_fin<<<BB, 320, 0, stream>>>(partial, stats);
    k2_feat<<<BB * TP, 256, 0, stream>>>(x, expnt, ipdf, stats, feat);
    k3_conv_ln<<<BB * TT, 512, 0, stream>>>(feat, wT, convb, lnw, lnb, out);
}

// Round 3
// 600.894 us; speedup vs baseline: 1.9328x; 1.9328x over previous
//
#include <hip/hip_runtime.h>
#include <math.h>

// Problem constants
#define BB 4
#define TT 512
#define FF 257
#define NP 10
#define DM 128
#define C2P 20              // 2*P channels
#define KW 5                // conv taps
#define TP 516              // T padded with 2-row zero halo on each side
#define FROW 288            // feat row stride in floats; word = (f&15)*18 + (f>>4)
#define CHSTRIDE (TP * FROW)        // 148608 floats per channel
#define BSTRIDE (C2P * CHSTRIDE)    // 2972160 floats per batch

// Workspace (floats): stats @0 (10280) ; wT @10304 (12800) ; feat @23104
// (11,888,640).  Total = 47.6 MB.  k1 partials (148,032) OVERLAY feat @23104
// (dead before k2 writes feat).

// ---------------------------------------------------------------------------
// K1a: partial per-(b,f) sums over 32-t chunks (blocks < BB*144), PLUS the
// weight transpose folded in as 50 extra blocks (saves a launch).
// wT[(p*10 + r)*128 + d], r = cl*5 + tap.
// partial[((b*257+f)*16 + c)*9 + k]: k=0..3 sum_re, 4..7 sum_im, 8 sum_sq
// ---------------------------------------------------------------------------
__global__ __launch_bounds__(256) void k1a_part(const float* __restrict__ x,
                                                float* __restrict__ partial,
                                                const float* __restrict__ convw,
                                                float* __restrict__ wT) {
    const int bid = blockIdx.x;
    if (bid >= BB * 144) {          // ---- weight-transpose blocks ----
        const int idx = (bid - BB * 144) * 256 + threadIdx.x;
        if (idx < NP * 10 * DM) {
            const int p = idx / 1280;
            const int rr = idx - p * 1280;
            const int r = rr >> 7, d = rr & 127;
            const int cl = r / 5, kt = r - cl * 5;
            wT[idx] = convw[(size_t)d * (C2P * KW) + (2 * p + cl) * KW + kt];
        }
        return;
    }
    const int b = bid / 144;
    const int rem = bid - b * 144;
    const int ft = rem >> 4;          // 0..8
    const int c = rem & 15;           // t-chunk 0..15
    const int tid = threadIdx.x;
    const int fi = tid & 31;
    const int th = tid >> 5;          // 0..7
    const int f = ft * 32 + fi;

    float s[9];
    #pragma unroll
    for (int k = 0; k < 9; k++) s[k] = 0.f;
    if (f < FF) {
        #pragma unroll
        for (int q = 0; q < 4; q++) {
            const int t = c * 32 + th * 4 + q;
            const float* px = x + (((size_t)b * TT + t) * FF + f) * 8;
            const float4 v0 = *(const float4*)px;
            const float4 v1 = *(const float4*)(px + 4);
            s[0] += v0.x; s[1] += v0.y; s[2] += v0.z; s[3] += v0.w;
            s[4] += v1.x; s[5] += v1.y; s[6] += v1.z; s[7] += v1.w;
            s[8] += v0.x*v0.x + v0.y*v0.y + v0.z*v0.z + v0.w*v0.w
                  + v1.x*v1.x + v1.y*v1.y + v1.z*v1.z + v1.w*v1.w;
        }
    }
    __shared__ float red[256][9];
    #pragma unroll
    for (int k = 0; k < 9; k++) red[tid][k] = s[k];
    __syncthreads();
    for (int st = 4; st >= 1; st >>= 1) {
        if (th < st) {
            #pragma unroll
            for (int k = 0; k < 9; k++) red[tid][k] += red[tid + 32 * st][k];
        }
        __syncthreads();
    }
    if (th == 0 && f < FF) {
        float* pp = partial + ((size_t)(b * FF + f) * 16 + c) * 9;
        #pragma unroll
        for (int k = 0; k < 9; k++) pp[k] = red[tid][k];
    }
}

// ---------------------------------------------------------------------------
// K1b: finalize stats from 16 chunk-partials.
// stats[b][f][10]: 0..3 mean_re, 4..7 mean_im, 8 inv_norm
// ---------------------------------------------------------------------------
__global__ __launch_bounds__(320) void k1b_fin(const float* __restrict__ partial,
                                               float* __restrict__ stats) {
    const int b = blockIdx.x;
    const int f = threadIdx.x;
    if (f >= FF) return;
    const float* pp = partial + (size_t)(b * FF + f) * 16 * 9;
    float s[9];
    #pragma unroll
    for (int k = 0; k < 9; k++) s[k] = 0.f;
    for (int c = 0; c < 16; c++) {
        #pragma unroll
        for (int k = 0; k < 9; k++) s[k] += pp[c * 9 + k];
    }
    const float invT = 1.0f / (float)TT;
    float pw = s[8] * invT;
    float* st = stats + ((size_t)b * FF + f) * 10;
    #pragma unroll
    for (int m = 0; m < 4; m++) {
        const float mr = s[m] * invT;
        const float mi = s[4 + m] * invT;
        st[m] = mr; st[4 + m] = mi;
        pw -= mr * mr + mi * mi;
    }
    st[8] = rsqrtf(fmaxf(pw, 1e-10f));
}

// ---------------------------------------------------------------------------
// K2: compute SCM features ONCE, stored PRE-SWIZZLED in k3's LDS word order:
// feat[b][ch][tpad][ w=(f&15)*18+(f>>4) ], row stride 288, invalid words = 0.
// Computed into an LDS row buffer (scatter stays in LDS), written out with
// fully coalesced float4 stores. Halo rows tpad in {0,1,514,515} all-zero.
// ---------------------------------------------------------------------------
__global__ __launch_bounds__(256) void k2_feat(const float* __restrict__ x,
                                               const float* __restrict__ expnt,
                                               const float* __restrict__ ipdf,
                                               const float* __restrict__ stats,
                                               float* __restrict__ feat) {
    const int b = blockIdx.x / TP;
    const int tpad = blockIdx.x % TP;
    const int t = tpad - 2;
    const int tid = threadIdx.x;
    float* fb = feat + (size_t)b * BSTRIDE + (size_t)tpad * FROW;  // + ch*CHSTRIDE

    if (t < 0 || t >= TT) {          // zero halo rows
        const float4 z = {0.f, 0.f, 0.f, 0.f};
        for (int i = tid; i < C2P * (FROW / 4); i += 256) {
            const int ch = i / (FROW / 4);
            const int w4 = i - ch * (FROW / 4);
            *(float4*)(fb + (size_t)ch * CHSTRIDE + w4 * 4) = z;
        }
        return;
    }

    __shared__ __align__(16) float rows[C2P * FROW];   // 23040 B
    for (int i = tid; i < C2P * FROW; i += 256) rows[i] = 0.f;
    __syncthreads();

    for (int f = tid; f < FF; f += 256) {
        const float* px = x + (((size_t)b * TT + t) * FF + f) * 8;
        const float4 v0 = *(const float4*)px;
        const float4 v1 = *(const float4*)(px + 4);
        const float* st = stats + ((size_t)b * FF + f) * 10;
        const float inv = st[8];
        float xr[4], xi[4];
        xr[0] = (v0.x - st[0]) * inv; xr[1] = (v0.y - st[1]) * inv;
        xr[2] = (v0.z - st[2]) * inv; xr[3] = (v0.w - st[3]) * inv;
        xi[0] = (v1.x - st[4]) * inv; xi[1] = (v1.y - st[5]) * inv;
        xi[2] = (v1.z - st[6]) * inv; xi[3] = (v1.w - st[7]) * inv;
        const float sef = 1.0f / (1.0f + __expf(-expnt[f]));
        const float sif = 1.0f / (1.0f + __expf(-ipdf[f]));
        const int sw = (f & 15) * 18 + (f >> 4);   // swizzled word within row
        const int MA[NP] = {0,0,0,0,1,1,1,2,2,3};
        const int MB[NP] = {0,1,2,3,1,2,3,2,3,3};
        #pragma unroll
        for (int p = 0; p < NP; p++) {
            const float cra = xr[MA[p]], cia = xi[MA[p]];
            const float crb = xr[MB[p]], cib = xi[MB[p]];
            const float re = cra * crb + cia * cib;
            const float im = cia * crb - cra * cib;
            const float r = sqrtf(re * re + im * im);
            const float bp = exp2f(sef * __log2f(r));   // r=0 -> 0 (matches ref)
            const float a = r / (bp + 1e-10f);
            const float ang = atan2f(im, re) * sif;
            float sn, cs;
            __sincosf(ang, &sn, &cs);
            rows[(2 * p) * FROW + sw] = a * cs;
            rows[(2 * p + 1) * FROW + sw] = a * sn;
        }
    }
    __syncthreads();

    // coalesced write-out: 20 rows x 288 words
    for (int i = tid; i < C2P * (FROW / 4); i += 256) {
        const int ch = i / (FROW / 4);
        const int w4 = i - ch * (FROW / 4);
        *(float4*)(fb + (size_t)ch * CHSTRIDE + w4 * 4) = *(float4*)&rows[ch * FROW + w4 * 4];
    }
}

// ---------------------------------------------------------------------------
// K3: one block per (b,t). Staged GEMM over 10 pairs + fused LayerNorm.
// 512 thr = 32 d-threads (4 d) x 16 f-threads (17 f, f = ftid+16j).
//
// Round-2 post-mortem: persistent reg-double-buffer (25 regs across the GEMM)
// + acc[4][17] cannot fit 128 VGPRs -> 1.9 GB scratch spill. This version has
// ZERO persistent staging registers:
//  - all conv weights staged to LDS once in the prologue (51.2 KB),
//  - k2 pre-swizzled feat, so per-pair staging is a LINEAR copy:
//    720 float4 (2 transient loads/thread), issued BEFORE the barrier so L2
//    latency hides under the barrier wait. 2 barriers/pair.
// LDS total ~63 KB -> 2 blocks/CU; VGPR ~110 -> no spill (verify: VGPR<128).
// ---------------------------------------------------------------------------
__global__ __launch_bounds__(512, 2) void k3_conv_ln(
        const float* __restrict__ feat,
        const float* __restrict__ wT,
        const float* __restrict__ convb,
        const float* __restrict__ lnw,
        const float* __restrict__ lnb,
        float* __restrict__ out) {
    const int bid = blockIdx.x;
    const int bt = (bid & 7) * 256 + (bid >> 3);  // XCD swizzle (2048 % 8 == 0)
    const int b = bt >> 9;
    const int t = bt & 511;
    const int tid = threadIdx.x;
    const int ftid = tid & 15;
    const int dtid = tid >> 4;      // 0..31
    const int d0 = dtid * 4;

    __shared__ __align__(16) float wAll[NP * 10 * DM];  // 51200 B
    __shared__ __align__(16) float fbuf[10 * FROW];     // 11520 B (rows r=cl*5+kt)
    __shared__ float wred[16];

    // prologue: stage ALL weights, linear float4 copy (3200 float4)
    for (int i = tid; i < 3200; i += 512)
        *(float4*)&wAll[4 * i] = *(const float4*)&wT[4 * i];

    // loop-invariant staging geometry: 720 float4 per pair (2 regions x 360)
    const size_t base0 = (size_t)b * BSTRIDE + (size_t)t * FROW;
    const int cla = (tid >= 360) ? 1 : 0;
    const int wa_ = (tid - cla * 360) * 4;        // word offset within region
    const int wb_ = (tid + 512 - 360) * 4;        // slot B: always region 1
    const bool hasB = (tid < 208);                // 720 - 512

    float acc[4][17];
    #pragma unroll
    for (int i = 0; i < 4; i++)
        #pragma unroll
        for (int j = 0; j < 17; j++) acc[i][j] = 0.f;

    #pragma unroll 1
    for (int p = 0; p < NP; p++) {
        // issue loads BEFORE the barrier (no hazard: they read global)
        const float4 va = *(const float4*)(feat + base0 + (size_t)(2 * p + cla) * CHSTRIDE + wa_);
        float4 vb;
        if (hasB) vb = *(const float4*)(feat + base0 + (size_t)(2 * p + 1) * CHSTRIDE + wb_);
        __syncthreads();                 // all waves done reading fbuf (pair p-1)
        *(float4*)&fbuf[cla * 1440 + wa_] = va;
        if (hasB) *(float4*)&fbuf[1440 + wb_] = vb;
        __syncthreads();                 // fbuf (and, at p=0, wAll) ready

        #pragma unroll
        for (int r = 0; r < 10; r++) {
            const float4 w = *(const float4*)&wAll[(p * 10 + r) * DM + d0];
            const float* bp_ = &fbuf[r * FROW + ftid * 18];
            const float2 q0 = *(const float2*)(bp_ + 0);
            const float2 q1 = *(const float2*)(bp_ + 2);
            const float2 q2 = *(const float2*)(bp_ + 4);
            const float2 q3 = *(const float2*)(bp_ + 6);
            const float2 q4 = *(const float2*)(bp_ + 8);
            const float2 q5 = *(const float2*)(bp_ + 10);
            const float2 q6 = *(const float2*)(bp_ + 12);
            const float2 q7 = *(const float2*)(bp_ + 14);
            const float fx = bp_[16];   // f=256+ftid: true 0 for ftid>0 (k2 zero-pad)
            const float fv[17] = {q0.x,q0.y,q1.x,q1.y,q2.x,q2.y,q3.x,q3.y,
                                  q4.x,q4.y,q5.x,q5.y,q6.x,q6.y,q7.x,q7.y,fx};
            const float wa4[4] = {w.x, w.y, w.z, w.w};
            #pragma unroll
            for (int i = 0; i < 4; i++)
                #pragma unroll
                for (int j = 0; j < 17; j++)
                    acc[i][j] = fmaf(wa4[i], fv[j], acc[i][j]);
        }
    }

    // ---- Epilogue: bias + LayerNorm over (d, f<257), coalesced stores ----
    float cb[4];
    #pragma unroll
    for (int i = 0; i < 4; i++) cb[i] = convb[d0 + i];

    float s1 = 0.f, s2 = 0.f;
    const int jmax = (ftid == 0) ? 17 : 16;   // f = ftid + 16*j < 257
    #pragma unroll
    for (int i = 0; i < 4; i++) {
        #pragma unroll
        for (int j = 0; j < 17; j++) {
            acc[i][j] += cb[i];
            if (j < jmax) { s1 += acc[i][j]; s2 += acc[i][j] * acc[i][j]; }
        }
    }
    #pragma unroll
    for (int off = 32; off >= 1; off >>= 1) {
        s1 += __shfl_down(s1, off, 64);
        s2 += __shfl_down(s2, off, 64);
    }
    const int wv8 = tid >> 6;                 // 8 waves
    if ((tid & 63) == 0) { wred[wv8] = s1; wred[8 + wv8] = s2; }
    __syncthreads();
    float S1 = 0.f, S2 = 0.f;
    #pragma unroll
    for (int w = 0; w < 8; w++) { S1 += wred[w]; S2 += wred[8 + w]; }
    const float Ninv = 1.0f / (float)(DM * FF);
    const float mu = S1 * Ninv;
    const float var = S2 * Ninv - mu * mu;
    const float rstd = rsqrtf(var + 1e-5f);

    float* op = out + (size_t)bt * DM * FF;
    #pragma unroll
    for (int i = 0; i < 4; i++) {
        const int d = d0 + i;
        #pragma unroll
        for (int j = 0; j < 17; j++) {
            const int f = ftid + 16 * j;
            if (f < FF) {
                const size_t o = (size_t)d * FF + f;
                op[o] = (acc[i][j] - mu) * rstd * lnw[o] + lnb[o];
            }
        }
    }
}

extern "C" void kernel_launch(void* const* d_in, const int* in_sizes, int n_in,
                              void* d_out, int out_size, void* d_ws, size_t ws_size,
                              hipStream_t stream) {
    const float* x     = (const float*)d_in[0];
    const float* expnt = (const float*)d_in[1];
    const float* ipdf  = (const float*)d_in[2];
    const float* convw = (const float*)d_in[3];
    const float* convb = (const float*)d_in[4];
    const float* lnw   = (const float*)d_in[5];
    const float* lnb   = (const float*)d_in[6];
    float* out = (float*)d_out;

    // stats 10280 @0 ; wT 12800 @10304 ; feat 11,888,640 @23104  (47.6 MB)
    float* stats   = (float*)d_ws;
    float* wT      = stats + 10304;
    float* feat    = stats + 23104;
    float* partial = feat;          // overlay: dead before k2 writes feat

    k1a_part<<<BB * 144 + 50, 256, 0, stream>>>(x, partial, convw, wT);
    k1b_fin<<<BB, 320, 0, stream>>>(partial, stats);
    k2_feat<<<BB * TP, 256, 0, stream>>>(x, expnt, ipdf, stats, feat);
    k3_conv_ln<<<BB * TT, 512, 0, stream>>>(feat, wT, convb, lnw, lnb, out);
}